// Round 1
// baseline (1526.503 us; speedup 1.0000x reference)
//
#include <hip/hip_runtime.h>

// SIREN forward: 5 sine layers.
//  x0 = sin(5*(coords @ W0^T + b0))   (N,2)->(N,64)
//  x1..x3 = sin(5*(x @ Wi^T + bi))    (N,64)->(N,64)
//  out = sin(5*(x3 @ W4^T + b4))      (N,64)->(N,128), f32
//
// Baseline strategy: 1 thread = 1 point. Activations live entirely in VGPRs
// (full unroll -> static indexing -> mem2reg). Weights are read at uniform,
// compile-time-constant offsets from __restrict__ const pointers so the
// backend emits scalar (s_load) reads and SGPR-operand v_fmac -- no LDS, no
// per-lane weight traffic. Compute-bound on fp32 VALU (~262us FMA floor).

#define OMEGA 5.0f

__device__ __forceinline__ void hidden_layer(const float* __restrict__ x,
                                             float* __restrict__ y,
                                             const float* __restrict__ W,
                                             const float* __restrict__ b) {
    #pragma unroll
    for (int j = 0; j < 64; ++j) {
        float acc = b[j];
        #pragma unroll
        for (int k = 0; k < 64; ++k) {
            acc = fmaf(x[k], W[j * 64 + k], acc);
        }
        y[j] = __sinf(OMEGA * acc);
    }
}

__global__ __launch_bounds__(256) void siren_f32_kernel(
    const float* __restrict__ coords,
    const float* __restrict__ W0, const float* __restrict__ b0,
    const float* __restrict__ W1, const float* __restrict__ b1,
    const float* __restrict__ W2, const float* __restrict__ b2,
    const float* __restrict__ W3, const float* __restrict__ b3,
    const float* __restrict__ W4, const float* __restrict__ b4,
    float* __restrict__ out, int n)
{
    int i = blockIdx.x * blockDim.x + threadIdx.x;
    if (i >= n) return;

    float2 c = *reinterpret_cast<const float2*>(coords + 2ull * i);

    float x[64], y[64];

    // Layer 0: (2 -> 64)
    #pragma unroll
    for (int j = 0; j < 64; ++j) {
        float acc = fmaf(c.x, W0[2 * j], fmaf(c.y, W0[2 * j + 1], b0[j]));
        x[j] = __sinf(OMEGA * acc);
    }

    // Layers 1-3: (64 -> 64), ping-pong x <-> y
    hidden_layer(x, y, W1, b1);
    hidden_layer(y, x, W2, b2);
    hidden_layer(x, y, W3, b3);

    // Layer 4: (64 -> 128), computed in float4 chunks to cap VGPR pressure,
    // stored immediately.
    float* outp = out + (size_t)i * 128;
    #pragma unroll
    for (int jc = 0; jc < 128; jc += 4) {
        float4 o;
        float* op = &o.x;
        #pragma unroll
        for (int jj = 0; jj < 4; ++jj) {
            int j = jc + jj;
            float acc = b4[j];
            #pragma unroll
            for (int k = 0; k < 64; ++k) {
                acc = fmaf(y[k], W4[j * 64 + k], acc);
            }
            op[jj] = __sinf(OMEGA * acc);
        }
        *reinterpret_cast<float4*>(outp + jc) = o;
    }
}

extern "C" void kernel_launch(void* const* d_in, const int* in_sizes, int n_in,
                              void* d_out, int out_size, void* d_ws, size_t ws_size,
                              hipStream_t stream) {
    const float* coords = (const float*)d_in[0];
    const float* W0 = (const float*)d_in[1];
    const float* b0 = (const float*)d_in[2];
    const float* W1 = (const float*)d_in[3];
    const float* b1 = (const float*)d_in[4];
    const float* W2 = (const float*)d_in[5];
    const float* b2 = (const float*)d_in[6];
    const float* W3 = (const float*)d_in[7];
    const float* b3 = (const float*)d_in[8];
    const float* W4 = (const float*)d_in[9];
    const float* b4 = (const float*)d_in[10];
    float* out = (float*)d_out;

    int n = in_sizes[0] / 2;  // coords is (N, 2)
    dim3 block(256);
    dim3 grid((n + 255) / 256);
    hipLaunchKernelGGL(siren_f32_kernel, grid, block, 0, stream,
                       coords, W0, b0, W1, b1, W2, b2, W3, b3, W4, b4, out, n);
}

// Round 2
// 473.367 us; speedup vs baseline: 3.2248x; 3.2248x over previous
//
#include <hip/hip_runtime.h>

// SIREN forward, MFMA version.
//   z1..z4: 16x16x32 f16 MFMA, activations carried transposed (Z = X^T) so
//   Z_l = sin( (5*W_l) x Z_{l-1} + 5*b_l ).  D-fragment of layer l IS the
//   B-fragment of layer l+1 under the k-slot convention
//   k = 32b + 16*(e>>2) + 4*(lane>>4) + (e&3)  -- applied consistently to A
//   (weights, pre-gathered into LDS frag tables) and B (activations), which
//   makes the result invariant to the true HW k-ordering (A/B symmetric).
// Layer 0 (K=2) in fp32 VALU to preserve coord precision; fp16 (not bf16)
// everywhere else for the 2^-11 rounding (error budget: ~1e-2 < 2e-2 thr).

typedef _Float16 half8 __attribute__((ext_vector_type(8)));
typedef float f32x4 __attribute__((ext_vector_type(4)));

#define OMEGA 5.0f

__global__ __launch_bounds__(256, 3) void siren_mfma_kernel(
    const float* __restrict__ coords,
    const float* __restrict__ W0, const float* __restrict__ b0,
    const float* __restrict__ W1, const float* __restrict__ b1,
    const float* __restrict__ W2, const float* __restrict__ b2,
    const float* __restrict__ W3, const float* __restrict__ b3,
    const float* __restrict__ W4, const float* __restrict__ b4,
    float* __restrict__ out, int n)
{
    // Pre-gathered A-fragment tables: [kblock][mtile][lane] -> 8 f16 (16 B).
    __shared__ half8 AT[3][2][4][64];    // hidden layers W1..W3: 3 x 8 KB
    __shared__ half8 AT4[2][8][64];      // W4: 16 KB
    __shared__ float4 w0tab[64];         // {5*W0[n][0], 5*W0[n][1], 5*b0[n], 0}
    __shared__ __align__(16) float btab[3][64];   // 5*b1..b3
    __shared__ __align__(16) float b4tab[128];    // 5*b4

    const int tid  = threadIdx.x;
    const int lane = tid & 63;
    const int g    = lane >> 4;        // lane group 0..3

    // ---------------- prep: build fragment tables ----------------
    {
        const float* Wp[3] = {W1, W2, W3};
        #pragma unroll
        for (int L = 0; L < 3; ++L) {
            #pragma unroll
            for (int c = 0; c < 2; ++c) {
                int chunk = (tid >> 6) + 4 * c;      // 0..7 = b*4 + mt
                int b  = chunk >> 2, mt = chunk & 3;
                const float* src = Wp[L] + (16 * mt + (lane & 15)) * 64 + 32 * b + 4 * g;
                float4 wa = *(const float4*)(src);
                float4 wb = *(const float4*)(src + 16);
                half8 h;
                h[0] = (_Float16)(OMEGA * wa.x); h[1] = (_Float16)(OMEGA * wa.y);
                h[2] = (_Float16)(OMEGA * wa.z); h[3] = (_Float16)(OMEGA * wa.w);
                h[4] = (_Float16)(OMEGA * wb.x); h[5] = (_Float16)(OMEGA * wb.y);
                h[6] = (_Float16)(OMEGA * wb.z); h[7] = (_Float16)(OMEGA * wb.w);
                AT[L][b][mt][lane] = h;
            }
        }
        #pragma unroll
        for (int c = 0; c < 4; ++c) {
            int chunk = (tid >> 6) + 4 * c;          // 0..15 = b*8 + mt
            int b  = chunk >> 3, mt = chunk & 7;
            const float* src = W4 + (16 * mt + (lane & 15)) * 64 + 32 * b + 4 * g;
            float4 wa = *(const float4*)(src);
            float4 wb = *(const float4*)(src + 16);
            half8 h;
            h[0] = (_Float16)(OMEGA * wa.x); h[1] = (_Float16)(OMEGA * wa.y);
            h[2] = (_Float16)(OMEGA * wa.z); h[3] = (_Float16)(OMEGA * wa.w);
            h[4] = (_Float16)(OMEGA * wb.x); h[5] = (_Float16)(OMEGA * wb.y);
            h[6] = (_Float16)(OMEGA * wb.z); h[7] = (_Float16)(OMEGA * wb.w);
            AT4[b][mt][lane] = h;
        }
        if (tid < 64) {
            w0tab[tid] = make_float4(OMEGA * W0[2 * tid], OMEGA * W0[2 * tid + 1],
                                     OMEGA * b0[tid], 0.f);
            btab[0][tid] = OMEGA * b1[tid];
            btab[1][tid] = OMEGA * b2[tid];
            btab[2][tid] = OMEGA * b3[tid];
        }
        if (tid < 128) b4tab[tid] = OMEGA * b4[tid];
    }
    __syncthreads();

    // ---------------- main loop: one wave = 16 points per batch ----------------
    const int p  = lane & 15;                 // point-in-batch (= MFMA column)
    const int nb = (n + 15) >> 4;
    const int wv = blockIdx.x * 4 + (tid >> 6);
    const int nw = gridDim.x * 4;

    for (int batch = wv; batch < nb; batch += nw) {
        int point = batch * 16 + p;
        int pt    = point < n ? point : n - 1;
        float2 c2 = *(const float2*)(coords + 2ull * (unsigned)pt);

        // Layer 0 (fp32 VALU): lane computes Z0[n][p] for n = 16t+4g+r,
        // landing directly in B-fragment slots: zb[t>>1][4*(t&1)+r].
        half8 zb[2];
        #pragma unroll
        for (int t = 0; t < 4; ++t) {
            #pragma unroll
            for (int r = 0; r < 4; ++r) {
                float4 w = w0tab[16 * t + 4 * g + r];
                float z = __sinf(fmaf(c2.x, w.x, fmaf(c2.y, w.y, w.z)));
                zb[t >> 1][4 * (t & 1) + r] = (_Float16)z;
            }
        }

        // Hidden layers 1..3
        #pragma unroll
        for (int L = 0; L < 3; ++L) {
            f32x4 acc[4];
            #pragma unroll
            for (int t = 0; t < 4; ++t) {
                float4 bv = *(const float4*)&btab[L][16 * t + 4 * g];
                acc[t][0] = bv.x; acc[t][1] = bv.y; acc[t][2] = bv.z; acc[t][3] = bv.w;
            }
            #pragma unroll
            for (int b = 0; b < 2; ++b) {
                #pragma unroll
                for (int mt = 0; mt < 4; ++mt) {
                    acc[mt] = __builtin_amdgcn_mfma_f32_16x16x32_f16(
                        AT[L][b][mt][lane], zb[b], acc[mt], 0, 0, 0);
                }
            }
            // activation + repack: D-regs -> next B-frags, all in-lane
            half8 zn[2];
            #pragma unroll
            for (int t = 0; t < 4; ++t) {
                #pragma unroll
                for (int r = 0; r < 4; ++r) {
                    zn[t >> 1][4 * (t & 1) + r] = (_Float16)__sinf(acc[t][r]);
                }
            }
            zb[0] = zn[0]; zb[1] = zn[1];
        }

        // Output layer: 64 -> 128, sin, store f32
        float* op = out + (size_t)point * 128;
        #pragma unroll
        for (int mt = 0; mt < 8; ++mt) {
            float4 bv = *(const float4*)&b4tab[16 * mt + 4 * g];
            f32x4 a4;
            a4[0] = bv.x; a4[1] = bv.y; a4[2] = bv.z; a4[3] = bv.w;
            a4 = __builtin_amdgcn_mfma_f32_16x16x32_f16(AT4[0][mt][lane], zb[0], a4, 0, 0, 0);
            a4 = __builtin_amdgcn_mfma_f32_16x16x32_f16(AT4[1][mt][lane], zb[1], a4, 0, 0, 0);
            float4 o = make_float4(__sinf(a4[0]), __sinf(a4[1]), __sinf(a4[2]), __sinf(a4[3]));
            if (point < n) {
                *(float4*)(op + 16 * mt + 4 * g) = o;
            }
        }
    }
}

extern "C" void kernel_launch(void* const* d_in, const int* in_sizes, int n_in,
                              void* d_out, int out_size, void* d_ws, size_t ws_size,
                              hipStream_t stream) {
    const float* coords = (const float*)d_in[0];
    const float* W0 = (const float*)d_in[1];
    const float* b0 = (const float*)d_in[2];
    const float* W1 = (const float*)d_in[3];
    const float* b1 = (const float*)d_in[4];
    const float* W2 = (const float*)d_in[5];
    const float* b2 = (const float*)d_in[6];
    const float* W3 = (const float*)d_in[7];
    const float* b3 = (const float*)d_in[8];
    const float* W4 = (const float*)d_in[9];
    const float* b4 = (const float*)d_in[10];
    float* out = (float*)d_out;

    int n = in_sizes[0] / 2;  // coords is (N, 2)
    int nb = (n + 15) / 16;
    int blocks = 768;         // 3 blocks/CU (LDS-limited), 4 waves each
    int maxb = (nb + 3) / 4;
    if (blocks > maxb) blocks = maxb;
    hipLaunchKernelGGL(siren_mfma_kernel, dim3(blocks), dim3(256), 0, stream,
                       coords, W0, b0, W1, b1, W2, b2, W3, b3, W4, b4, out, n);
}

// Round 4
// 471.738 us; speedup vs baseline: 3.2359x; 1.0035x over previous
//
#include <hip/hip_runtime.h>

// SIREN forward, MFMA version, round 4: coalesced full-line output stores.
// (Round 3 failed to compile: __builtin_nontemporal_store needs a native
//  clang vector type, not HIP's float4 class. Mechanical fix, same design.)
//
// Round-2 counters showed 2.1 GB HBM traffic vs 0.55 GB ideal: the D-fragment
// layout (lane -> (neuron row, point col)) made each global store instruction
// write 16 scattered 64 B half-lines -> partial-line write-allocate fetches
// (FETCH_SIZE 1.43 GB) + write amplification (657 MB).
// Fix: per-wave LDS transpose of each 16-point x 32-col output slab, then
// fully-coalesced 1KB-per-instruction nontemporal float4 stores (full 128 B
// lines, no L2 allocation).

typedef _Float16 half8 __attribute__((ext_vector_type(8)));
typedef float f32x4 __attribute__((ext_vector_type(4)));

#define OMEGA 5.0f

__global__ __launch_bounds__(256, 3) void siren_mfma_kernel(
    const float* __restrict__ coords,
    const float* __restrict__ W0, const float* __restrict__ b0,
    const float* __restrict__ W1, const float* __restrict__ b1,
    const float* __restrict__ W2, const float* __restrict__ b2,
    const float* __restrict__ W3, const float* __restrict__ b3,
    const float* __restrict__ W4, const float* __restrict__ b4,
    float* __restrict__ out, int n)
{
    // Pre-gathered A-fragment tables: [kblock][mtile][lane] -> 8 f16 (16 B).
    __shared__ half8 AT[3][2][4][64];    // hidden layers W1..W3: 3 x 8 KB
    __shared__ half8 AT4[2][8][64];      // W4: 16 KB
    __shared__ float4 w0tab[64];         // {5*W0[n][0], 5*W0[n][1], 5*b0[n], 0}
    __shared__ __align__(16) float btab[3][64];   // 5*b1..b3
    __shared__ __align__(16) float b4tab[128];    // 5*b4
    // Per-wave output transpose slab: 16 points x 32 cols, padded to 36
    // (row stride 144 B: write-side bank aliasing 2-way max = free).
    __shared__ float stage[4][16][36];   // 9 KB

    const int tid  = threadIdx.x;
    const int lane = tid & 63;
    const int g    = lane >> 4;        // lane group 0..3
    const int w    = tid >> 6;         // wave in block

    // ---------------- prep: build fragment tables ----------------
    {
        const float* Wp[3] = {W1, W2, W3};
        #pragma unroll
        for (int L = 0; L < 3; ++L) {
            #pragma unroll
            for (int c = 0; c < 2; ++c) {
                int chunk = w + 4 * c;               // 0..7 = b*4 + mt
                int b  = chunk >> 2, mt = chunk & 3;
                const float* src = Wp[L] + (16 * mt + (lane & 15)) * 64 + 32 * b + 4 * g;
                float4 wa = *(const float4*)(src);
                float4 wb = *(const float4*)(src + 16);
                half8 h;
                h[0] = (_Float16)(OMEGA * wa.x); h[1] = (_Float16)(OMEGA * wa.y);
                h[2] = (_Float16)(OMEGA * wa.z); h[3] = (_Float16)(OMEGA * wa.w);
                h[4] = (_Float16)(OMEGA * wb.x); h[5] = (_Float16)(OMEGA * wb.y);
                h[6] = (_Float16)(OMEGA * wb.z); h[7] = (_Float16)(OMEGA * wb.w);
                AT[L][b][mt][lane] = h;
            }
        }
        #pragma unroll
        for (int c = 0; c < 4; ++c) {
            int chunk = w + 4 * c;                   // 0..15 = b*8 + mt
            int b  = chunk >> 3, mt = chunk & 7;
            const float* src = W4 + (16 * mt + (lane & 15)) * 64 + 32 * b + 4 * g;
            float4 wa = *(const float4*)(src);
            float4 wb = *(const float4*)(src + 16);
            half8 h;
            h[0] = (_Float16)(OMEGA * wa.x); h[1] = (_Float16)(OMEGA * wa.y);
            h[2] = (_Float16)(OMEGA * wa.z); h[3] = (_Float16)(OMEGA * wa.w);
            h[4] = (_Float16)(OMEGA * wb.x); h[5] = (_Float16)(OMEGA * wb.y);
            h[6] = (_Float16)(OMEGA * wb.z); h[7] = (_Float16)(OMEGA * wb.w);
            AT4[b][mt][lane] = h;
        }
        if (tid < 64) {
            w0tab[tid] = make_float4(OMEGA * W0[2 * tid], OMEGA * W0[2 * tid + 1],
                                     OMEGA * b0[tid], 0.f);
            btab[0][tid] = OMEGA * b1[tid];
            btab[1][tid] = OMEGA * b2[tid];
            btab[2][tid] = OMEGA * b3[tid];
        }
        if (tid < 128) b4tab[tid] = OMEGA * b4[tid];
    }
    __syncthreads();

    // ---------------- main loop: one wave = 16 points per batch ----------------
    const int p  = lane & 15;                 // point-in-batch (= MFMA column)
    const int j8 = lane >> 3;                 // 0..7   (store-side point index)
    const int k8 = lane & 7;                  // 0..7   (store-side col index)
    const int nb = (n + 15) >> 4;
    const int wv = blockIdx.x * 4 + w;
    const int nw = gridDim.x * 4;

    for (int batch = wv; batch < nb; batch += nw) {
        int point = batch * 16 + p;
        int pt    = point < n ? point : n - 1;
        float2 c2 = *(const float2*)(coords + 2ull * (unsigned)pt);

        // Layer 0 (fp32 VALU): lane computes Z0[n][p] for n = 16t+4g+r,
        // landing directly in B-fragment slots: zb[t>>1][4*(t&1)+r].
        half8 zb[2];
        #pragma unroll
        for (int t = 0; t < 4; ++t) {
            #pragma unroll
            for (int r = 0; r < 4; ++r) {
                float4 ww = w0tab[16 * t + 4 * g + r];
                float z = __sinf(fmaf(c2.x, ww.x, fmaf(c2.y, ww.y, ww.z)));
                zb[t >> 1][4 * (t & 1) + r] = (_Float16)z;
            }
        }

        // Hidden layers 1..3
        #pragma unroll
        for (int L = 0; L < 3; ++L) {
            f32x4 acc[4];
            #pragma unroll
            for (int t = 0; t < 4; ++t) {
                float4 bv = *(const float4*)&btab[L][16 * t + 4 * g];
                acc[t][0] = bv.x; acc[t][1] = bv.y; acc[t][2] = bv.z; acc[t][3] = bv.w;
            }
            #pragma unroll
            for (int b = 0; b < 2; ++b) {
                #pragma unroll
                for (int mt = 0; mt < 4; ++mt) {
                    acc[mt] = __builtin_amdgcn_mfma_f32_16x16x32_f16(
                        AT[L][b][mt][lane], zb[b], acc[mt], 0, 0, 0);
                }
            }
            // activation + repack: D-regs -> next B-frags, all in-lane
            half8 zn[2];
            #pragma unroll
            for (int t = 0; t < 4; ++t) {
                #pragma unroll
                for (int r = 0; r < 4; ++r) {
                    zn[t >> 1][4 * (t & 1) + r] = (_Float16)__sinf(acc[t][r]);
                }
            }
            zb[0] = zn[0]; zb[1] = zn[1];
        }

        // Output layer: 64 -> 128 in four 32-col slabs. Each slab: 2 mt-tiles
        // of MFMA+sin -> per-wave LDS transpose -> 2 fully-coalesced 1 KB
        // nontemporal store instructions (full 128 B lines).
        const size_t rowbase = (size_t)(batch * 16) * 128;
        #pragma unroll
        for (int q = 0; q < 4; ++q) {
            #pragma unroll
            for (int m = 0; m < 2; ++m) {
                int mt = 2 * q + m;
                float4 bv = *(const float4*)&b4tab[16 * mt + 4 * g];
                f32x4 a4;
                a4[0] = bv.x; a4[1] = bv.y; a4[2] = bv.z; a4[3] = bv.w;
                a4 = __builtin_amdgcn_mfma_f32_16x16x32_f16(AT4[0][mt][lane], zb[0], a4, 0, 0, 0);
                a4 = __builtin_amdgcn_mfma_f32_16x16x32_f16(AT4[1][mt][lane], zb[1], a4, 0, 0, 0);
                f32x4 o;
                o[0] = __sinf(a4[0]); o[1] = __sinf(a4[1]);
                o[2] = __sinf(a4[2]); o[3] = __sinf(a4[3]);
                *(f32x4*)&stage[w][p][16 * m + 4 * g] = o;
            }
            // read back transposed + coalesced NT store (compiler inserts
            // the lgkmcnt wait for the same-wave ds_write->ds_read dep; no
            // __syncthreads needed: slab is wave-private).
            #pragma unroll
            for (int i = 0; i < 2; ++i) {
                int pp = 8 * i + j8;
                f32x4 o4 = *(const f32x4*)&stage[w][pp][4 * k8];
                int pointp = batch * 16 + pp;
                if (pointp < n) {
                    float* gp = out + rowbase + (size_t)pp * 128 + 32 * q + 4 * k8;
                    __builtin_nontemporal_store(o4, (f32x4*)gp);
                }
            }
        }
    }
}

extern "C" void kernel_launch(void* const* d_in, const int* in_sizes, int n_in,
                              void* d_out, int out_size, void* d_ws, size_t ws_size,
                              hipStream_t stream) {
    const float* coords = (const float*)d_in[0];
    const float* W0 = (const float*)d_in[1];
    const float* b0 = (const float*)d_in[2];
    const float* W1 = (const float*)d_in[3];
    const float* b1 = (const float*)d_in[4];
    const float* W2 = (const float*)d_in[5];
    const float* b2 = (const float*)d_in[6];
    const float* W3 = (const float*)d_in[7];
    const float* b3 = (const float*)d_in[8];
    const float* W4 = (const float*)d_in[9];
    const float* b4 = (const float*)d_in[10];
    float* out = (float*)d_out;

    int n = in_sizes[0] / 2;  // coords is (N, 2)
    int nb = (n + 15) / 16;
    int blocks = 768;         // 3 blocks/CU (LDS-limited), 4 waves each
    int maxb = (nb + 3) / 4;
    if (blocks > maxb) blocks = maxb;
    hipLaunchKernelGGL(siren_mfma_kernel, dim3(blocks), dim3(256), 0, stream,
                       coords, W0, b0, W1, b1, W2, b2, W3, b3, W4, b4, out, n);
}

// Round 5
// 325.715 us; speedup vs baseline: 4.6866x; 1.4483x over previous
//
#include <hip/hip_runtime.h>

// SIREN forward, MFMA, round 5: maximal store contiguity.
//
// Round-4 lesson: full 128-B-line stores + NT did NOT remove the 1.43 GB
// FETCH_SIZE -> the write-allocate/RMW granule is larger than 128 B. Only
// remaining 1.4-GB-scale candidate is store-induced line fills, so this round
// each store instruction writes 1 KB fully contiguous (two complete 512-B
// point rows), 8 back-to-back instructions per 8-KB batch, via a full
// 16x128 f32 LDS slab per wave (chunk-XOR swizzled, conflict-free).
// Plain cached stores (no NT) -- single-variable test of contiguity.

typedef _Float16 half8 __attribute__((ext_vector_type(8)));
typedef float f32x4 __attribute__((ext_vector_type(4)));

#define OMEGA 5.0f

__global__ __launch_bounds__(256, 2) void siren_mfma_kernel(
    const float* __restrict__ coords,
    const float* __restrict__ W0, const float* __restrict__ b0,
    const float* __restrict__ W1, const float* __restrict__ b1,
    const float* __restrict__ W2, const float* __restrict__ b2,
    const float* __restrict__ W3, const float* __restrict__ b3,
    const float* __restrict__ W4, const float* __restrict__ b4,
    float* __restrict__ out, int n)
{
    // Pre-gathered A-fragment tables: [kblock][mtile][lane] -> 8 f16 (16 B).
    __shared__ half8 AT[3][2][4][64];    // hidden layers W1..W3: 24 KB
    __shared__ half8 AT4[2][8][64];      // W4: 16 KB
    __shared__ float4 w0tab[64];         // {5*W0[n][0], 5*W0[n][1], 5*b0[n], 0}
    __shared__ __align__(16) float btab[3][64];   // 5*b1..b3
    __shared__ __align__(16) float b4tab[128];    // 5*b4
    // Per-wave full output slab: 16 points x 128 cols f32 (8 KB/wave, 32 KB).
    // float4-chunk XOR swizzle (chunk ^= row&7): balanced banks on both the
    // MFMA-side b128 writes and the store-side b128 reads.
    __shared__ float stage[4][16][128];

    const int tid  = threadIdx.x;
    const int lane = tid & 63;
    const int g    = lane >> 4;        // lane group 0..3
    const int w    = tid >> 6;         // wave in block

    // ---------------- prep: build fragment tables ----------------
    {
        const float* Wp[3] = {W1, W2, W3};
        #pragma unroll
        for (int L = 0; L < 3; ++L) {
            #pragma unroll
            for (int c = 0; c < 2; ++c) {
                int chunk = w + 4 * c;               // 0..7 = b*4 + mt
                int b  = chunk >> 2, mt = chunk & 3;
                const float* src = Wp[L] + (16 * mt + (lane & 15)) * 64 + 32 * b + 4 * g;
                float4 wa = *(const float4*)(src);
                float4 wb = *(const float4*)(src + 16);
                half8 h;
                h[0] = (_Float16)(OMEGA * wa.x); h[1] = (_Float16)(OMEGA * wa.y);
                h[2] = (_Float16)(OMEGA * wa.z); h[3] = (_Float16)(OMEGA * wa.w);
                h[4] = (_Float16)(OMEGA * wb.x); h[5] = (_Float16)(OMEGA * wb.y);
                h[6] = (_Float16)(OMEGA * wb.z); h[7] = (_Float16)(OMEGA * wb.w);
                AT[L][b][mt][lane] = h;
            }
        }
        #pragma unroll
        for (int c = 0; c < 4; ++c) {
            int chunk = w + 4 * c;                   // 0..15 = b*8 + mt
            int b  = chunk >> 3, mt = chunk & 7;
            const float* src = W4 + (16 * mt + (lane & 15)) * 64 + 32 * b + 4 * g;
            float4 wa = *(const float4*)(src);
            float4 wb = *(const float4*)(src + 16);
            half8 h;
            h[0] = (_Float16)(OMEGA * wa.x); h[1] = (_Float16)(OMEGA * wa.y);
            h[2] = (_Float16)(OMEGA * wa.z); h[3] = (_Float16)(OMEGA * wa.w);
            h[4] = (_Float16)(OMEGA * wb.x); h[5] = (_Float16)(OMEGA * wb.y);
            h[6] = (_Float16)(OMEGA * wb.z); h[7] = (_Float16)(OMEGA * wb.w);
            AT4[b][mt][lane] = h;
        }
        if (tid < 64) {
            w0tab[tid] = make_float4(OMEGA * W0[2 * tid], OMEGA * W0[2 * tid + 1],
                                     OMEGA * b0[tid], 0.f);
            btab[0][tid] = OMEGA * b1[tid];
            btab[1][tid] = OMEGA * b2[tid];
            btab[2][tid] = OMEGA * b3[tid];
        }
        if (tid < 128) b4tab[tid] = OMEGA * b4[tid];
    }
    __syncthreads();

    // ---------------- main loop: one wave = 16 points per batch ----------------
    const int p   = lane & 15;                // point-in-batch (= MFMA column)
    const int sr  = lane >> 5;                // store-side row parity (0/1)
    const int sc  = lane & 31;                // store-side float4 chunk 0..31
    const int nb  = (n + 15) >> 4;
    const int wv  = blockIdx.x * 4 + w;
    const int nw  = gridDim.x * 4;

    for (int batch = wv; batch < nb; batch += nw) {
        int point = batch * 16 + p;
        int pt    = point < n ? point : n - 1;
        float2 c2 = *(const float2*)(coords + 2ull * (unsigned)pt);

        // Layer 0 (fp32 VALU): lane computes Z0[n][p] for n = 16t+4g+r,
        // landing directly in B-fragment slots: zb[t>>1][4*(t&1)+r].
        half8 zb[2];
        #pragma unroll
        for (int t = 0; t < 4; ++t) {
            #pragma unroll
            for (int r = 0; r < 4; ++r) {
                float4 ww = w0tab[16 * t + 4 * g + r];
                float z = __sinf(fmaf(c2.x, ww.x, fmaf(c2.y, ww.y, ww.z)));
                zb[t >> 1][4 * (t & 1) + r] = (_Float16)z;
            }
        }

        // Hidden layers 1..3
        #pragma unroll
        for (int L = 0; L < 3; ++L) {
            f32x4 acc[4];
            #pragma unroll
            for (int t = 0; t < 4; ++t) {
                float4 bv = *(const float4*)&btab[L][16 * t + 4 * g];
                acc[t][0] = bv.x; acc[t][1] = bv.y; acc[t][2] = bv.z; acc[t][3] = bv.w;
            }
            #pragma unroll
            for (int b = 0; b < 2; ++b) {
                #pragma unroll
                for (int mt = 0; mt < 4; ++mt) {
                    acc[mt] = __builtin_amdgcn_mfma_f32_16x16x32_f16(
                        AT[L][b][mt][lane], zb[b], acc[mt], 0, 0, 0);
                }
            }
            // activation + repack: D-regs -> next B-frags, all in-lane
            half8 zn[2];
            #pragma unroll
            for (int t = 0; t < 4; ++t) {
                #pragma unroll
                for (int r = 0; r < 4; ++r) {
                    zn[t >> 1][4 * (t & 1) + r] = (_Float16)__sinf(acc[t][r]);
                }
            }
            zb[0] = zn[0]; zb[1] = zn[1];
        }

        // Output layer: 64 -> 128, all 8 mt-tiles into the per-wave LDS slab
        // (chunk-XOR swizzle), then 8 fully-contiguous 1 KB store instructions.
        #pragma unroll
        for (int mt = 0; mt < 8; ++mt) {
            float4 bv = *(const float4*)&b4tab[16 * mt + 4 * g];
            f32x4 a4;
            a4[0] = bv.x; a4[1] = bv.y; a4[2] = bv.z; a4[3] = bv.w;
            a4 = __builtin_amdgcn_mfma_f32_16x16x32_f16(AT4[0][mt][lane], zb[0], a4, 0, 0, 0);
            a4 = __builtin_amdgcn_mfma_f32_16x16x32_f16(AT4[1][mt][lane], zb[1], a4, 0, 0, 0);
            f32x4 o;
            o[0] = __sinf(a4[0]); o[1] = __sinf(a4[1]);
            o[2] = __sinf(a4[2]); o[3] = __sinf(a4[3]);
            int chunk = (4 * mt + g) ^ (p & 7);      // float4-chunk swizzle
            *(f32x4*)&stage[w][p][4 * chunk] = o;
        }
        // Store: instruction i writes point rows 2i (lanes 0-31) and 2i+1
        // (lanes 32-63) -- 1 KB contiguous per instruction, 8 KB back-to-back.
        const float* sbase = &stage[w][0][0];
        #pragma unroll
        for (int i = 0; i < 8; ++i) {
            int row = 2 * i + sr;
            int cs  = sc ^ (row & 7);
            f32x4 o4 = *(const f32x4*)(sbase + 128 * row + 4 * cs);
            int pointp = batch * 16 + row;
            if (pointp < n) {
                *(f32x4*)(out + (size_t)pointp * 128 + 4 * sc) = o4;
            }
        }
    }
}

extern "C" void kernel_launch(void* const* d_in, const int* in_sizes, int n_in,
                              void* d_out, int out_size, void* d_ws, size_t ws_size,
                              hipStream_t stream) {
    const float* coords = (const float*)d_in[0];
    const float* W0 = (const float*)d_in[1];
    const float* b0 = (const float*)d_in[2];
    const float* W1 = (const float*)d_in[3];
    const float* b1 = (const float*)d_in[4];
    const float* W2 = (const float*)d_in[5];
    const float* b2 = (const float*)d_in[6];
    const float* W3 = (const float*)d_in[7];
    const float* b3 = (const float*)d_in[8];
    const float* W4 = (const float*)d_in[9];
    const float* b4 = (const float*)d_in[10];
    float* out = (float*)d_out;

    int n = in_sizes[0] / 2;  // coords is (N, 2)
    int nb = (n + 15) / 16;
    int blocks = 512;         // 2 blocks/CU (74.3 KB LDS), 4 waves each
    int maxb = (nb + 3) / 4;
    if (blocks > maxb) blocks = maxb;
    hipLaunchKernelGGL(siren_mfma_kernel, dim3(blocks), dim3(256), 0, stream,
                       coords, W0, b0, W1, b1, W2, b2, W3, b3, W4, b4, out, n);
}